// Round 2
// baseline (626.678 us; speedup 1.0000x reference)
//
#include <hip/hip_runtime.h>

// DCT_Layer: fixed 4x4 2D-DCT grouped conv, padding=2, then min(|out|, 8).
// x: (8, 3, 512, 512) fp32  ->  out: (8, 48, 513, 513) fp32
//
// v3 structure: ONE OUTPUT PLANE PER BLOCK-COLUMN (grid.y = 384 = 24 bc x 16
// coeff). Writes stream sequentially per plane (fill-like), fixing the
// 16-plane x 1MB-stride write scatter that held v1/v2 at ~2.2 TB/s effective.
// kk/ll are wave-uniform -> the transform is a 4-tap horizontal dot per input
// row (coeffs via uniform scalar selects, edge masks folded into the coeffs)
// + a sliding 4-tap vertical dot over a 16-row strip (19 h values -> 16 outs).
// All borders handled by address clamp + zero-mask: no edge kernel, no
// divergent exec juggling. Lanes consecutive in ow => dense 256B loads/stores.

#define IHW 512
#define OHW 513
#define PLANE ((size_t)OHW * (size_t)OHW)
#define RSTRIP 16
#define NSTRIP 33                 // ceil(513/16); last strip clamps to oh0=497
#define JOB_T (513 * NSTRIP)      // 16929 work items per plane

__global__ __launch_bounds__(256) void dct_plane(const float* __restrict__ x,
                                                 float* __restrict__ out) {
    const float A1 = 0.6532814824381883f;   // sqrt(.5)*cos(pi/8)
    const float A2 = 0.2705980500730985f;   // sqrt(.5)*cos(3pi/8)

    int t = blockIdx.x * 256 + threadIdx.x;
    if (t >= JOB_T) return;
    int j = blockIdx.y;           // plane id = bc*16 + kk*4 + ll
    int bc = j >> 4;
    int kk = (j >> 2) & 3;
    int ll = j & 3;

    int s = t / 513;              // strip index (compiler magic-div)
    int ow = t - s * 513;         // 0..512, lane-consecutive
    int oh0 = s * RSTRIP;
    if (oh0 > OHW - RSTRIP) oh0 = OHW - RSTRIP;   // 497 (overlap rows recompute
                                                  // identical values: benign)

    // DCT basis row a[m] = {m==0: .5,.5,.5,.5 | m==1: A1,A2,-A2,-A1 |
    //                       m==2: .5,-.5,-.5,.5 | m==3: A2,-A1,A1,-A2}
    // horizontal (ll) coeffs — wave-uniform scalar selects
    float g0 = (ll == 0) ? 0.5f : (ll == 1) ?  A1 : (ll == 2) ?  0.5f :  A2;
    float g1 = (ll == 0) ? 0.5f : (ll == 1) ?  A2 : (ll == 2) ? -0.5f : -A1;
    float g2 = (ll == 0) ? 0.5f : (ll == 1) ? -A2 : (ll == 2) ? -0.5f :  A1;
    float g3 = (ll == 0) ? 0.5f : (ll == 1) ? -A1 : (ll == 2) ?  0.5f : -A2;
    // vertical (kk) coeffs
    float c0 = (kk == 0) ? 0.5f : (kk == 1) ?  A1 : (kk == 2) ?  0.5f :  A2;
    float c1 = (kk == 0) ? 0.5f : (kk == 1) ?  A2 : (kk == 2) ? -0.5f : -A1;
    float c2 = (kk == 0) ? 0.5f : (kk == 1) ? -A2 : (kk == 2) ? -0.5f :  A1;
    float c3 = (kk == 0) ? 0.5f : (kk == 1) ? -A1 : (kk == 2) ?  0.5f : -A2;

    // column offsets: clamp address (always-safe loads), fold validity into g
    int iw0 = ow - 2;
    int i0 = min(max(iw0,     0), IHW - 1);
    int i1 = min(max(iw0 + 1, 0), IHW - 1);
    int i2 = min(max(iw0 + 2, 0), IHW - 1);
    int i3 = min(max(iw0 + 3, 0), IHW - 1);
    float gm0 = ((unsigned)iw0       < (unsigned)IHW) ? g0 : 0.0f;
    float gm1 = ((unsigned)(iw0 + 1) < (unsigned)IHW) ? g1 : 0.0f;
    float gm2 = ((unsigned)(iw0 + 2) < (unsigned)IHW) ? g2 : 0.0f;
    float gm3 = ((unsigned)(iw0 + 3) < (unsigned)IHW) ? g3 : 0.0f;

    const float* __restrict__ xin = x + (size_t)bc * (IHW * IHW);

    // horizontal pass: 19 input rows -> h[0..18]; row validity via cndmask
    float h[RSTRIP + 3];
#pragma unroll
    for (int i = 0; i < RSTRIP + 3; ++i) {
        int ih = oh0 - 2 + i;
        int ihc = min(max(ih, 0), IHW - 1);
        const float* __restrict__ row = xin + ihc * IHW;
        float v = gm0 * row[i0] + gm1 * row[i1] + gm2 * row[i2] + gm3 * row[i3];
        h[i] = ((unsigned)ih < (unsigned)IHW) ? v : 0.0f;
    }

    // vertical pass + store: streaming, dense per wave, one plane per job
    float* __restrict__ op = out + (size_t)j * PLANE + (size_t)oh0 * OHW + ow;
#pragma unroll
    for (int o = 0; o < RSTRIP; ++o) {
        float v = c0 * h[o] + c1 * h[o + 1] + c2 * h[o + 2] + c3 * h[o + 3];
        op[(size_t)o * OHW] = fminf(fabsf(v), 8.0f);
    }
}

extern "C" void kernel_launch(void* const* d_in, const int* in_sizes, int n_in,
                              void* d_out, int out_size, void* d_ws, size_t ws_size,
                              hipStream_t stream) {
    const float* x = (const float*)d_in[0];
    float* out = (float*)d_out;
    dim3 grid((JOB_T + 255) / 256, 384);   // 67 x 384 blocks, 256 threads
    hipLaunchKernelGGL(dct_plane, grid, dim3(256), 0, stream, x, out);
}

// Round 3
// 472.648 us; speedup vs baseline: 1.3259x; 1.3259x over previous
//
#include <hip/hip_runtime.h>

// DCT_Layer: fixed 4x4 2D-DCT grouped conv, padding=2, then min(|out|, 8).
// x: (8, 3, 512, 512) fp32  ->  out: (8, 48, 513, 513) fp32
//
// v5: block = (bc, 4-row strip). Stage 7 input rows once into LDS (float4,
// zero-padded borders), compute horizontal DCT into registers (2 cols/thread,
// 4 ll each, butterfly), then vertical butterfly for all 16 (kk,ll) planes and
// store. Key properties:
//  - each block writes 16 contiguous 8.2 KB streams (4 full rows per plane);
//    adjacent blockIdx.x = adjacent rows -> long per-plane sequential writes
//    (fixes the 1KB-chunk scatter that capped v1/v3 at ~2.2/1.5 TB/s).
//  - input staged ONCE per block (no 16x re-read); all coeffs are literals
//    (full unroll), all border handling via LDS zero-pad: no masks in compute.
//  - lane = column => every load/store dense-coalesced (256 B / wave instr).

#define IHW 512
#define OHW 513
#define PLANE ((size_t)OHW * (size_t)OHW)
#define RS 4                    // output rows per block
#define NS 129                  // ceil(513/4) strips (last clamps, dup rows ok)
#define XW 520                  // LDS row pitch in floats (pad 4 left)

__global__ __launch_bounds__(256) void dct_v5(const float* __restrict__ x,
                                              float* __restrict__ out) {
    const float A1 = 0.6532814824381883f;   // sqrt(.5)*cos(pi/8)
    const float A2 = 0.2705980500730985f;   // sqrt(.5)*cos(3pi/8)

    // xs[i][p] = x[r0-2+i][p-4]; zeros at p=2,3 (iw=-2,-1) and 516,517 (iw=512,513)
    __shared__ float xs[7 * XW];

    const int t = threadIdx.x;
    const int bc = blockIdx.y;                 // 0..23
    int r0 = blockIdx.x * RS;
    if (r0 > OHW - RS) r0 = OHW - RS;          // 509 on last strip (dup rows, same values)

    const float* __restrict__ xin = x + (size_t)bc * ((size_t)IHW * IHW);

    // ---- stage: rows r0-2 .. r0+4 (7 rows x 512 cols) ----
    if (r0 >= 2 && r0 + RS <= IHW - 1) {
        // fully interior: one contiguous 7*512-float span, float4 loads
        const float4* __restrict__ src = (const float4*)(xin + (size_t)(r0 - 2) * IHW);
#pragma unroll
        for (int k = 0; k < 4; ++k) {
            int idx = t + k * 256;             // 0..895 vec4s
            if (idx < 896) {
                float4 v = src[idx];
                int f = idx << 2;
                int i = f >> 9;                // row 0..6
                int c = f & 511;               // col, %4==0
                float* d = &xs[i * XW + 4 + c];   // 16B-aligned
                d[0] = v.x; d[1] = v.y; d[2] = v.z; d[3] = v.w;
            }
        }
    } else {
        // edge strip: per-row clamped scalar loads, zero invalid rows
#pragma unroll
        for (int i = 0; i < 7; ++i) {
            int ih = r0 - 2 + i;
            bool rv = (unsigned)ih < (unsigned)IHW;
            const float* __restrict__ row = xin + (size_t)(rv ? ih : 0) * IHW;
#pragma unroll
            for (int k = 0; k < 2; ++k) {
                int c = t + k * 256;
                float v = row[c];
                xs[i * XW + 4 + c] = rv ? v : 0.0f;
            }
        }
    }
    if (t < 7) {    // side zero-pads
        xs[t * XW + 2]   = 0.0f;
        xs[t * XW + 3]   = 0.0f;
        xs[t * XW + 516] = 0.0f;
        xs[t * XW + 517] = 0.0f;
    }
    __syncthreads();

    // ---- horizontal DCT: cols t and t+256, h[ll][i] in registers ----
    // h[ll][ow] = sum_j a[ll][j] * x[ih][ow-2+j] = butterfly over xs[i][ow+2 .. ow+5]
    float h0[4][7], h1[4][7];
#pragma unroll
    for (int i = 0; i < 7; ++i) {
        const float* __restrict__ r = &xs[i * XW + 2 + t];
        {
            float v0 = r[0], v1 = r[1], v2 = r[2], v3 = r[3];
            float s03 = v0 + v3, d03 = v0 - v3, s12 = v1 + v2, d12 = v1 - v2;
            h0[0][i] = 0.5f * (s03 + s12);
            h0[1][i] = A1 * d03 + A2 * d12;
            h0[2][i] = 0.5f * (s03 - s12);
            h0[3][i] = A2 * d03 - A1 * d12;
        }
        {
            float v0 = r[256], v1 = r[257], v2 = r[258], v3 = r[259];
            float s03 = v0 + v3, d03 = v0 - v3, s12 = v1 + v2, d12 = v1 - v2;
            h1[0][i] = 0.5f * (s03 + s12);
            h1[1][i] = A1 * d03 + A2 * d12;
            h1[2][i] = 0.5f * (s03 - s12);
            h1[3][i] = A2 * d03 - A1 * d12;
        }
    }

    // ---- vertical DCT + store: out[kk*4+ll][r0+o][col] ----
    const size_t oc = (size_t)bc * 16 * PLANE + (size_t)r0 * OHW;
#pragma unroll
    for (int o = 0; o < RS; ++o) {
        size_t rowoff = oc + (size_t)o * OHW;
#pragma unroll
        for (int ll = 0; ll < 4; ++ll) {
            float s03a = h0[ll][o] + h0[ll][o + 3], d03a = h0[ll][o] - h0[ll][o + 3];
            float s12a = h0[ll][o + 1] + h0[ll][o + 2], d12a = h0[ll][o + 1] - h0[ll][o + 2];
            float s03b = h1[ll][o] + h1[ll][o + 3], d03b = h1[ll][o] - h1[ll][o + 3];
            float s12b = h1[ll][o + 1] + h1[ll][o + 2], d12b = h1[ll][o + 1] - h1[ll][o + 2];

            float ua0 = 0.5f * (s03a + s12a), ub0 = 0.5f * (s03b + s12b);
            float ua1 = A1 * d03a + A2 * d12a, ub1 = A1 * d03b + A2 * d12b;
            float ua2 = 0.5f * (s03a - s12a), ub2 = 0.5f * (s03b - s12b);
            float ua3 = A2 * d03a - A1 * d12a, ub3 = A2 * d03b - A1 * d12b;

            out[rowoff + (size_t)(0 * 4 + ll) * PLANE + t]       = fminf(fabsf(ua0), 8.0f);
            out[rowoff + (size_t)(0 * 4 + ll) * PLANE + t + 256] = fminf(fabsf(ub0), 8.0f);
            out[rowoff + (size_t)(1 * 4 + ll) * PLANE + t]       = fminf(fabsf(ua1), 8.0f);
            out[rowoff + (size_t)(1 * 4 + ll) * PLANE + t + 256] = fminf(fabsf(ub1), 8.0f);
            out[rowoff + (size_t)(2 * 4 + ll) * PLANE + t]       = fminf(fabsf(ua2), 8.0f);
            out[rowoff + (size_t)(2 * 4 + ll) * PLANE + t + 256] = fminf(fabsf(ub2), 8.0f);
            out[rowoff + (size_t)(3 * 4 + ll) * PLANE + t]       = fminf(fabsf(ua3), 8.0f);
            out[rowoff + (size_t)(3 * 4 + ll) * PLANE + t + 256] = fminf(fabsf(ub3), 8.0f);
        }
    }

    // ---- col 512 tail (one lane): h from xs[i][514..517] ----
    if (t == 0) {
        float h2[4][7];
#pragma unroll
        for (int i = 0; i < 7; ++i) {
            float v0 = xs[i * XW + 514], v1 = xs[i * XW + 515];
            float v2 = xs[i * XW + 516], v3 = xs[i * XW + 517];
            float s03 = v0 + v3, d03 = v0 - v3, s12 = v1 + v2, d12 = v1 - v2;
            h2[0][i] = 0.5f * (s03 + s12);
            h2[1][i] = A1 * d03 + A2 * d12;
            h2[2][i] = 0.5f * (s03 - s12);
            h2[3][i] = A2 * d03 - A1 * d12;
        }
#pragma unroll
        for (int o = 0; o < RS; ++o) {
#pragma unroll
            for (int ll = 0; ll < 4; ++ll) {
                float s03 = h2[ll][o] + h2[ll][o + 3], d03 = h2[ll][o] - h2[ll][o + 3];
                float s12 = h2[ll][o + 1] + h2[ll][o + 2], d12 = h2[ll][o + 1] - h2[ll][o + 2];
                float u0 = 0.5f * (s03 + s12);
                float u1 = A1 * d03 + A2 * d12;
                float u2 = 0.5f * (s03 - s12);
                float u3 = A2 * d03 - A1 * d12;
                size_t rowoff = oc + (size_t)o * OHW + 512;
                out[rowoff + (size_t)(0 * 4 + ll) * PLANE] = fminf(fabsf(u0), 8.0f);
                out[rowoff + (size_t)(1 * 4 + ll) * PLANE] = fminf(fabsf(u1), 8.0f);
                out[rowoff + (size_t)(2 * 4 + ll) * PLANE] = fminf(fabsf(u2), 8.0f);
                out[rowoff + (size_t)(3 * 4 + ll) * PLANE] = fminf(fabsf(u3), 8.0f);
            }
        }
    }
}

extern "C" void kernel_launch(void* const* d_in, const int* in_sizes, int n_in,
                              void* d_out, int out_size, void* d_ws, size_t ws_size,
                              hipStream_t stream) {
    const float* x = (const float*)d_in[0];
    float* out = (float*)d_out;
    dim3 grid(NS, 24);            // 129 strips x 24 (b,c) planes
    hipLaunchKernelGGL(dct_v5, grid, dim3(256), 0, stream, x, out);
}